// Round 17
// baseline (243.884 us; speedup 1.0000x reference)
//
#include <hip/hip_runtime.h>
#include <hip/hip_bf16.h>
#include <math.h>

// SparseAttention: B=8, N=2048, C=768, k=1638.
// r17 = r16 (238.6us) + proj retiled to 128x96 for exact grid packing
//       (3072 blocks = 6 full rounds @ 2 blk/CU; was 2304 = 4.5 rounds -> 5).
//   cast (merged): x->xb, W->Wb
//   proj (128x96 2-phase): QKb [M,1536] | Vt [B][C][N]
//   QK^T (256^2 8-phase, grid 512): Sb bf16 [8,N,N]
//   topk v2: histogram select + softmax -> Pb bf16     [HBM roofline]
//   PV (128x96 2-phase, grid 1024): out f32

typedef __attribute__((ext_vector_type(8))) short bf16x8;
typedef __attribute__((ext_vector_type(4))) float f32x4;

__device__ __forceinline__ unsigned short f2bf(float f) {
    unsigned u = __float_as_uint(f);
    unsigned r = u + 0x7FFFu + ((u >> 16) & 1u);   // RN-even
    return (unsigned short)(r >> 16);
}
__device__ __forceinline__ float bf2f(unsigned short h) {
    return __uint_as_float(((unsigned)h) << 16);
}

__device__ __forceinline__ void async16(const void* g, void* l) {
    __builtin_amdgcn_global_load_lds(
        (const __attribute__((address_space(1))) void*)g,
        (__attribute__((address_space(3))) void*)l, 16, 0, 0);
}

// ================= 128x96 2-phase proj core (PV96 geometry, EPI-5) =========
// A = xb [16384,768], B = Wb [2304,768] (NT). Grid (24,128) = 3072 blocks
// @ 2 blk/CU = exactly 6 rounds. Columns: bx<16 -> QKb; bx>=16 -> Vt.
__global__ __launch_bounds__(256) void gemm_proj96(
    const unsigned short* __restrict__ xb, const unsigned short* __restrict__ Wb,
    unsigned short* __restrict__ QKb, unsigned short* __restrict__ Vt)
{
    __shared__ unsigned short As[2][128 * 64];   // 2 x 16 KB
    __shared__ unsigned short Bs[2][96 * 64];    // 2 x 12 KB

    const int nx  = gridDim.x;                   // 24
    const int nwg = nx * gridDim.y;              // 3072
    const int flat = blockIdx.x + nx * blockIdx.y;
    const int lid  = (flat & 7) * (nwg >> 3) + (flat >> 3);
    const int bx   = lid % nx;
    const int by   = lid / nx;

    const int t    = threadIdx.x;
    const int wid  = t >> 6, lane = t & 63;
    const int wr   = wid >> 1, wc = wid & 1;     // 2x2 waves; wave = 64x48 out
    const int fr   = lane & 15, fq = lane >> 4;
    const int m0   = by * 128, n0 = bx * 96;

    const unsigned short* Ab0 = xb + (long)m0 * 768;
    const unsigned short* Bb0 = Wb + (long)n0 * 768;

    const int srow = t >> 3;                      // 0..31
    const int sgc  = ((t & 7) ^ (srow & 7)) * 8;  // inverse-swizzled source
    const char* pa[4];
    const char* pb[3];
#pragma unroll
    for (int i = 0; i < 4; ++i)
        pa[i] = (const char*)(Ab0 + (long)(i * 32 + srow) * 768 + sgc);
#pragma unroll
    for (int i = 0; i < 3; ++i)
        pb[i] = (const char*)(Bb0 + (long)(i * 32 + srow) * 768 + sgc);

    int aoffs[4][2], boffs[3][2];
#pragma unroll
    for (int m = 0; m < 4; ++m) {
        const int ra = wr * 64 + m * 16 + fr;     // ra&7 == fr&7
#pragma unroll
        for (int ks = 0; ks < 2; ++ks)
            aoffs[m][ks] = ra * 128 + (((ks * 4 + fq) ^ (ra & 7)) * 16);
    }
#pragma unroll
    for (int n = 0; n < 3; ++n) {
        const int rb = wc * 48 + n * 16 + fr;     // 48 % 8 == 0 -> rb&7 == fr&7
#pragma unroll
        for (int ks = 0; ks < 2; ++ks)
            boffs[n][ks] = rb * 128 + (((ks * 4 + fq) ^ (rb & 7)) * 16);
    }
    const char* AsBase = (const char*)&As[0][0];
    const char* BsBase = (const char*)&Bs[0][0];

    f32x4 acc[4][3];
#pragma unroll
    for (int m = 0; m < 4; ++m)
#pragma unroll
        for (int n = 0; n < 3; ++n) acc[m][n] = (f32x4)0.f;

    const int ldsT = wid * 1024;

#define STAGEPJ(kt, u)                                                        \
    {                                                                         \
        _Pragma("unroll")                                                     \
        for (int i = 0; i < 4; ++i)                                           \
            async16(pa[i] + (kt) * 128,                                       \
                    (char*)&As[(u)][0] + i * 4096 + ldsT);                    \
        _Pragma("unroll")                                                     \
        for (int i = 0; i < 3; ++i)                                           \
            async16(pb[i] + (kt) * 128,                                       \
                    (char*)&Bs[(u)][0] + i * 4096 + ldsT);                    \
    }

    STAGEPJ(0, 0);

#pragma unroll
    for (int tt = 0; tt < 12; ++tt) {             // K = 768 = 12 * 64
        if (tt + 1 < 12) {
            STAGEPJ(tt + 1, (tt + 1) & 1);        // 7 next-tile loads in flight
            asm volatile("s_waitcnt vmcnt(7)" ::: "memory");
        } else {
            asm volatile("s_waitcnt vmcnt(0)" ::: "memory");
        }
        __builtin_amdgcn_sched_barrier(0);
        __builtin_amdgcn_s_barrier();
        __builtin_amdgcn_sched_barrier(0);

        // buffer strides DIFFER: As = 16384 B, Bs = 12288 B (r10 lesson)
        const int abufo = (tt & 1) * 16384;
        const int bbufo = (tt & 1) * 12288;
        bf16x8 fA[4][2], fB[3][2];
#pragma unroll
        for (int m = 0; m < 4; ++m)
#pragma unroll
            for (int ks = 0; ks < 2; ++ks)
                fA[m][ks] = *(const bf16x8*)(AsBase + abufo + aoffs[m][ks]);
#pragma unroll
        for (int n = 0; n < 3; ++n)
#pragma unroll
            for (int ks = 0; ks < 2; ++ks)
                fB[n][ks] = *(const bf16x8*)(BsBase + bbufo + boffs[n][ks]);
        __builtin_amdgcn_s_setprio(1);
#pragma unroll
        for (int m = 0; m < 4; ++m)
#pragma unroll
            for (int n = 0; n < 3; ++n)
#pragma unroll
                for (int ks = 0; ks < 2; ++ks)
                    acc[m][n] = __builtin_amdgcn_mfma_f32_16x16x32_bf16(
                        fA[m][ks], fB[n][ks], acc[m][n], 0, 0, 0);
        __builtin_amdgcn_s_setprio(0);
        __builtin_amdgcn_sched_barrier(0);
        __builtin_amdgcn_s_barrier();
        __builtin_amdgcn_sched_barrier(0);
    }
#undef STAGEPJ

    // epilogue: block-uniform column split (1536/96 = 16 -> bx<16 is QK)
#pragma unroll
    for (int m = 0; m < 4; ++m) {
        const int gr0 = m0 + wr * 64 + m * 16 + fq * 4;
#pragma unroll
        for (int n = 0; n < 3; ++n) {
            const int gc = n0 + wc * 48 + n * 16 + fr;
            if (n0 < 1536) {
#pragma unroll
                for (int j = 0; j < 4; ++j)
                    QKb[(long)(gr0 + j) * 1536 + gc] = f2bf(acc[m][n][j]);
            } else {
                ushort4 p;
                p.x = f2bf(acc[m][n][0]); p.y = f2bf(acc[m][n][1]);
                p.z = f2bf(acc[m][n][2]); p.w = f2bf(acc[m][n][3]);
                const long idx =
                    ((long)(gr0 >> 11) * 768 + (gc - 1536)) * 2048 + (gr0 & 2047);
                *(ushort4*)&Vt[idx] = p;
            }
        }
    }
}

// ================= 128x96 2-phase PV core (r16, proven) ====================
__global__ __launch_bounds__(256) void gemm_pv96(
    const unsigned short* __restrict__ Pb, const unsigned short* __restrict__ Vt,
    float* __restrict__ out)
{
    __shared__ unsigned short As[2][128 * 64];   // 2 x 16 KB
    __shared__ unsigned short Bs[2][96 * 64];    // 2 x 12 KB

    const int nx  = gridDim.x, ny = gridDim.y;   // (8,16,8)
    const int nwg = nx * ny * gridDim.z;
    const int flat = blockIdx.x + nx * (blockIdx.y + ny * blockIdx.z);
    const int lid  = (flat & 7) * (nwg >> 3) + (flat >> 3);
    const int bx   = lid % nx;
    const int byz  = lid / nx;
    const int by   = byz % ny;
    const int bz   = byz / ny;

    const int t    = threadIdx.x;
    const int wid  = t >> 6, lane = t & 63;
    const int wr   = wid >> 1, wc = wid & 1;
    const int fr   = lane & 15, fq = lane >> 4;
    const int m0   = by * 128, n0 = bx * 96;

    const unsigned short* Ab0 = Pb + (long)bz * 2048 * 2048 + (long)m0 * 2048;
    const unsigned short* Bb0 = Vt + (long)bz * 768 * 2048 + (long)n0 * 2048;

    const int srow = t >> 3;
    const int sgc  = ((t & 7) ^ (srow & 7)) * 8;
    const char* pa[4];
    const char* pb[3];
#pragma unroll
    for (int i = 0; i < 4; ++i)
        pa[i] = (const char*)(Ab0 + (long)(i * 32 + srow) * 2048 + sgc);
#pragma unroll
    for (int i = 0; i < 3; ++i)
        pb[i] = (const char*)(Bb0 + (long)(i * 32 + srow) * 2048 + sgc);

    int aoffs[4][2], boffs[3][2];
#pragma unroll
    for (int m = 0; m < 4; ++m) {
        const int ra = wr * 64 + m * 16 + fr;
#pragma unroll
        for (int ks = 0; ks < 2; ++ks)
            aoffs[m][ks] = ra * 128 + (((ks * 4 + fq) ^ (ra & 7)) * 16);
    }
#pragma unroll
    for (int n = 0; n < 3; ++n) {
        const int rb = wc * 48 + n * 16 + fr;
#pragma unroll
        for (int ks = 0; ks < 2; ++ks)
            boffs[n][ks] = rb * 128 + (((ks * 4 + fq) ^ (rb & 7)) * 16);
    }
    const char* AsBase = (const char*)&As[0][0];
    const char* BsBase = (const char*)&Bs[0][0];

    f32x4 acc[4][3];
#pragma unroll
    for (int m = 0; m < 4; ++m)
#pragma unroll
        for (int n = 0; n < 3; ++n) acc[m][n] = (f32x4)0.f;

    const int ldsT = wid * 1024;

#define STAGEPV(kt, u)                                                        \
    {                                                                         \
        _Pragma("unroll")                                                     \
        for (int i = 0; i < 4; ++i)                                           \
            async16(pa[i] + (kt) * 128,                                       \
                    (char*)&As[(u)][0] + i * 4096 + ldsT);                    \
        _Pragma("unroll")                                                     \
        for (int i = 0; i < 3; ++i)                                           \
            async16(pb[i] + (kt) * 128,                                       \
                    (char*)&Bs[(u)][0] + i * 4096 + ldsT);                    \
    }

    STAGEPV(0, 0);

#pragma unroll
    for (int tt = 0; tt < 32; ++tt) {             // K = 2048 = 32 * 64
        if (tt + 1 < 32) {
            STAGEPV(tt + 1, (tt + 1) & 1);
            asm volatile("s_waitcnt vmcnt(7)" ::: "memory");
        } else {
            asm volatile("s_waitcnt vmcnt(0)" ::: "memory");
        }
        __builtin_amdgcn_sched_barrier(0);
        __builtin_amdgcn_s_barrier();
        __builtin_amdgcn_sched_barrier(0);

        const int abufo = (tt & 1) * 16384;
        const int bbufo = (tt & 1) * 12288;
        bf16x8 fA[4][2], fB[3][2];
#pragma unroll
        for (int m = 0; m < 4; ++m)
#pragma unroll
            for (int ks = 0; ks < 2; ++ks)
                fA[m][ks] = *(const bf16x8*)(AsBase + abufo + aoffs[m][ks]);
#pragma unroll
        for (int n = 0; n < 3; ++n)
#pragma unroll
            for (int ks = 0; ks < 2; ++ks)
                fB[n][ks] = *(const bf16x8*)(BsBase + bbufo + boffs[n][ks]);
        __builtin_amdgcn_s_setprio(1);
#pragma unroll
        for (int m = 0; m < 4; ++m)
#pragma unroll
            for (int n = 0; n < 3; ++n)
#pragma unroll
                for (int ks = 0; ks < 2; ++ks)
                    acc[m][n] = __builtin_amdgcn_mfma_f32_16x16x32_bf16(
                        fA[m][ks], fB[n][ks], acc[m][n], 0, 0, 0);
        __builtin_amdgcn_s_setprio(0);
        __builtin_amdgcn_sched_barrier(0);
        __builtin_amdgcn_s_barrier();
        __builtin_amdgcn_sched_barrier(0);
    }
#undef STAGEPV

    float* Cf = out + (long)bz * 2048 * 768;
#pragma unroll
    for (int m = 0; m < 4; ++m) {
        const int gr0 = m0 + wr * 64 + m * 16 + fq * 4;
#pragma unroll
        for (int n = 0; n < 3; ++n) {
            const int gc = n0 + wc * 48 + n * 16 + fr;
#pragma unroll
            for (int j = 0; j < 4; ++j)
                Cf[(long)(gr0 + j) * 768 + gc] = acc[m][n][j];
        }
    }
}

// ================== 256^2 8-phase core (r13-proven; QK^T) ==================
template <int NITER>
__global__ __launch_bounds__(512) void gemm8(
    const unsigned short* __restrict__ A0, const unsigned short* __restrict__ B0,
    int lda, int ldb, long batchA, long batchB,
    unsigned short* __restrict__ Cp0, int ldc, long batchC, float alpha)
{
    __shared__ unsigned short As[2][256 * 64];   // 2 x 32KB
    __shared__ unsigned short Bs[2][256 * 64];   // 2 x 32KB

    const int nx  = gridDim.x, ny = gridDim.y;
    const int nwg = nx * ny * gridDim.z;
    const int flat = blockIdx.x + nx * (blockIdx.y + ny * blockIdx.z);
    const int lid  = (flat & 7) * (nwg >> 3) + (flat >> 3);
    const int bx   = lid % nx;
    const int byz  = lid / nx;
    const int by   = byz % ny;
    const int bz   = byz / ny;

    const int t    = threadIdx.x;
    const int wid  = t >> 6, lane = t & 63;
    const int wr   = wid >> 2, wc = wid & 3;            // 2 x 4 waves
    const int fr   = lane & 15, fq = lane >> 4;
    const int m0   = by * 256, n0 = bx * 256;

    const unsigned short* Ab0 = A0 + (long)bz * batchA + (long)m0 * lda;
    const unsigned short* Bb0 = B0 + (long)bz * batchB + (long)n0 * ldb;

    const int srow = t >> 3;                  // 0..63
    const int sgc  = ((t & 7) ^ (srow & 7)) * 8;
    const char* pa[4];
    const char* pb[4];
#pragma unroll
    for (int i = 0; i < 4; ++i) {
        pa[i] = (const char*)(Ab0 + (long)(i * 64 + srow) * lda + sgc);
        pb[i] = (const char*)(Bb0 + (long)(i * 64 + srow) * ldb + sgc);
    }

    const int xo0 = ((fq    ) ^ (fr & 7)) * 16;
    const int xo1 = ((fq + 4) ^ (fr & 7)) * 16;
    const int abase = (wr * 128 + fr) * 128;
    const int bbase = (wc * 64  + fr) * 128;
    const char* AsB = (const char*)&As[0][0];
    const char* BsB = (const char*)&Bs[0][0];
    const int ldsT = wid * 1024;

    f32x4 acc[8][4];
#pragma unroll
    for (int m = 0; m < 8; ++m)
#pragma unroll
        for (int n = 0; n < 4; ++n) acc[m][n] = (f32x4)0.f;

#define SA_(h, kt)                                                            \
    { char* d = (char*)&As[(kt) & 1][0] + (h) * 16384 + ldsT;                 \
      async16(pa[2 * (h)]     + (long)(kt) * 128, d);                         \
      async16(pa[2 * (h) + 1] + (long)(kt) * 128, d + 8192); }
#define SB_(h, kt)                                                            \
    { char* d = (char*)&Bs[(kt) & 1][0] + (h) * 16384 + ldsT;                 \
      async16(pb[2 * (h)]     + (long)(kt) * 128, d);                         \
      async16(pb[2 * (h) + 1] + (long)(kt) * 128, d + 8192); }
#define BARRIER { __builtin_amdgcn_sched_barrier(0);                          \
                  __builtin_amdgcn_s_barrier();                               \
                  __builtin_amdgcn_sched_barrier(0); }
#define LG0 { asm volatile("s_waitcnt lgkmcnt(0)" ::: "memory");              \
              __builtin_amdgcn_sched_barrier(0); }
#define VM6 { asm volatile("s_waitcnt vmcnt(6)" ::: "memory");                \
              __builtin_amdgcn_sched_barrier(0); }
#define VM0 { asm volatile("s_waitcnt vmcnt(0)" ::: "memory");                \
              __builtin_amdgcn_sched_barrier(0); }
#define LDA4_(bp, mq)                                                         \
    _Pragma("unroll") for (int mi = 0; mi < 4; ++mi) {                        \
        fA[mi][0] = *(const bf16x8*)((bp) + abase + ((mq)*4+mi)*2048 + xo0);  \
        fA[mi][1] = *(const bf16x8*)((bp) + abase + ((mq)*4+mi)*2048 + xo1);  \
    }
#define LDB2_(bp, nb)                                                         \
    _Pragma("unroll") for (int ni = 0; ni < 2; ++ni) {                        \
        fB[(nb)+ni][0] = *(const bf16x8*)((bp) + bbase + ((nb)+ni)*2048 + xo0);\
        fB[(nb)+ni][1] = *(const bf16x8*)((bp) + bbase + ((nb)+ni)*2048 + xo1);\
    }
#define MM16_(mq, nq)                                                         \
    __builtin_amdgcn_s_setprio(1);                                            \
    _Pragma("unroll") for (int mi = 0; mi < 4; ++mi)                          \
    _Pragma("unroll") for (int ni = 0; ni < 2; ++ni)                          \
    _Pragma("unroll") for (int ks = 0; ks < 2; ++ks)                          \
        acc[(mq)*4+mi][(nq)*2+ni] = __builtin_amdgcn_mfma_f32_16x16x32_bf16(  \
            fA[mi][ks], fB[(nq)*2+ni][ks], acc[(mq)*4+mi][(nq)*2+ni], 0,0,0); \
    __builtin_amdgcn_s_setprio(0);

    // prologue: tile0 fully + tile1 {B0,B1,A0} = 14 loads; vmcnt(6) forces
    // tile0's 8 landed, leaves tile1's 6 in flight.
    SB_(0, 0); SB_(1, 0); SA_(0, 0); SA_(1, 0);
    SB_(0, 1); SB_(1, 1); SA_(0, 1);
    VM6; BARRIER;

    bf16x8 fA[4][2], fB[4][2];
#pragma unroll
    for (int it = 0; it < NITER; ++it) {
        const int tb = 2 * it + 1;
        const bool last = (it == NITER - 1);
        const char* A0p = AsB;
        const char* B0p = BsB;
        const char* A1p = AsB + 32768;
        const char* B1p = BsB + 32768;

        // ---- phases 1-4: tile 2i (buf0) ----
        LDA4_(A0p, 0); LDB2_(B0p, 0);
        SA_(1, tb);
        BARRIER; LG0; MM16_(0, 0); BARRIER;

        LDB2_(B0p, 2);
        BARRIER; LG0; MM16_(0, 1); BARRIER;

        LDA4_(A0p, 1);
        if (!last) SB_(0, tb + 1);
        BARRIER; LG0; MM16_(1, 0); BARRIER;

        if (!last) { SB_(1, tb + 1); SA_(0, tb + 1); }
        BARRIER;
        MM16_(1, 1);
        if (last) VM0 else VM6;
        BARRIER;

        // ---- phases 5-8: tile 2i+1 (buf1) ----
        LDA4_(A1p, 0); LDB2_(B1p, 0);
        if (!last) SA_(1, tb + 1);
        BARRIER; LG0; MM16_(0, 0); BARRIER;

        LDB2_(B1p, 2);
        BARRIER; LG0; MM16_(0, 1); BARRIER;

        LDA4_(A1p, 1);
        if (!last) SB_(0, tb + 2);
        BARRIER; LG0; MM16_(1, 0); BARRIER;

        if (!last) { SB_(1, tb + 2); SA_(0, tb + 2); }
        BARRIER;
        MM16_(1, 1);
        if (last) VM0 else VM6;
        BARRIER;
    }
#undef SA_
#undef SB_
#undef BARRIER
#undef LG0
#undef VM6
#undef VM0
#undef LDA4_
#undef LDB2_
#undef MM16_

    // ---- epilogue: bf16 + alpha, z-batched ----
    unsigned short* H = Cp0 + (long)bz * batchC;
#pragma unroll
    for (int m = 0; m < 8; ++m) {
        const int gr0 = m0 + wr * 128 + m * 16 + fq * 4;
#pragma unroll
        for (int n = 0; n < 4; ++n) {
            const int gc = n0 + wc * 64 + n * 16 + fr;
#pragma unroll
            for (int j = 0; j < 4; ++j)
                H[(long)(gr0 + j) * ldc + gc] = f2bf(alpha * acc[m][n][j]);
        }
    }
}

// ------------------- merged conversion: f32 -> bf16 planes -----------------
__global__ __launch_bounds__(256) void cast_both(
    const float* __restrict__ x, const float* __restrict__ W,
    unsigned short* __restrict__ xb, unsigned short* __restrict__ Wb,
    int nx8, int ntot8)
{
    const int i = blockIdx.x * 256 + threadIdx.x;
    if (i >= ntot8) return;
    const float* src;
    unsigned short* dst;
    int j;
    if (i < nx8) { src = x; dst = xb; j = i; }
    else         { src = W; dst = Wb; j = i - nx8; }
    const float4 a = ((const float4*)src)[j * 2];
    const float4 b = ((const float4*)src)[j * 2 + 1];
    ushort4 h0, h1;
    h0.x = f2bf(a.x); h0.y = f2bf(a.y); h0.z = f2bf(a.z); h0.w = f2bf(a.w);
    h1.x = f2bf(b.x); h1.y = f2bf(b.y); h1.z = f2bf(b.z); h1.w = f2bf(b.w);
    ((ushort4*)dst)[j * 2]     = h0;
    ((ushort4*)dst)[j * 2 + 1] = h1;
}

// ------------------------- top-k + softmax (v2) ----------------------------
#define ROWN 2048

__global__ __launch_bounds__(256) void topk_softmax_rows(
    const unsigned short* __restrict__ Sb, unsigned short* __restrict__ P,
    int kkeep)
{
    __shared__ __align__(16) unsigned hist[2048];
    __shared__ float    redmax[4], redmin[4], ssum[4];
    __shared__ unsigned wsum[4];
    __shared__ unsigned selBin;

    const unsigned short* row = Sb + (long)blockIdx.x * ROWN;
    unsigned short* prow = P + (long)blockIdx.x * ROWN;
    const int t    = threadIdx.x;
    const int lane = t & 63, w = t >> 6;

    float x[8];
    {
        const ushort4 a = ((const ushort4*)row)[t * 2];
        const ushort4 b = ((const ushort4*)row)[t * 2 + 1];
        x[0] = bf2f(a.x); x[1] = bf2f(a.y); x[2] = bf2f(a.z); x[3] = bf2f(a.w);
        x[4] = bf2f(b.x); x[5] = bf2f(b.y); x[6] = bf2f(b.z); x[7] = bf2f(b.w);
    }
    ((uint4*)hist)[t * 2]     = make_uint4(0, 0, 0, 0);
    ((uint4*)hist)[t * 2 + 1] = make_uint4(0, 0, 0, 0);

    float mx = x[0], mn = x[0];
#pragma unroll
    for (int j = 1; j < 8; ++j) { mx = fmaxf(mx, x[j]); mn = fminf(mn, x[j]); }
#pragma unroll
    for (int off = 32; off >= 1; off >>= 1) {
        mx = fmaxf(mx, __shfl_xor(mx, off, 64));
        mn = fminf(mn, __shfl_xor(mn, off, 64));
    }
    if (lane == 0) { redmax[w] = mx; redmin[w] = mn; }
    __syncthreads();
    mx = fmaxf(fmaxf(redmax[0], redmax[1]), fmaxf(redmax[2], redmax[3]));
    mn = fminf(fminf(redmin[0], redmin[1]), fminf(redmin[2], redmin[3]));

    const float scale = 2047.0f / fmaxf(mx - mn, 1e-30f);
    int q[8];
#pragma unroll
    for (int j = 0; j < 8; ++j) {
        int v = (int)((x[j] - mn) * scale);
        q[j] = v < 0 ? 0 : (v > 2047 ? 2047 : v);
        atomicAdd(&hist[q[j]], 1u);
    }
    __syncthreads();

    const uint4 h0 = ((const uint4*)hist)[t * 2];
    const uint4 h1 = ((const uint4*)hist)[t * 2 + 1];
    const unsigned hv[8] = { h0.x, h0.y, h0.z, h0.w, h1.x, h1.y, h1.z, h1.w };
    unsigned loc = 0;
#pragma unroll
    for (int j = 0; j < 8; ++j) loc += hv[j];
    unsigned s = loc;
#pragma unroll
    for (int off = 1; off <= 32; off <<= 1) {
        const unsigned o = __shfl_down(s, off, 64);
        s += (lane + off < 64) ? o : 0u;
    }
    if (lane == 0) wsum[w] = s;
    const unsigned texcl = s - loc;
    __syncthreads();
    unsigned above = texcl;
#pragma unroll
    for (int w2 = 0; w2 < 4; ++w2)
        if (w2 > w) above += wsum[w2];
    {
        unsigned cum = above;
        int hit = -1;
#pragma unroll
        for (int j = 7; j >= 0; --j) {
            const unsigned sp = cum;
            cum += hv[j];
            if (cum >= (unsigned)kkeep && sp < (unsigned)kkeep) hit = 8 * t + j;
        }
        if (hit >= 0) selBin = (unsigned)hit;
    }
    __syncthreads();
    const int bstar = (int)selBin;

    float e[8];
    float sum = 0.f;
#pragma unroll
    for (int j = 0; j < 8; ++j) {
        e[j] = (q[j] >= bstar) ? __expf(x[j] - mx) : 0.f;
        sum += e[j];
    }
#pragma unroll
    for (int off = 32; off >= 1; off >>= 1)
        sum += __shfl_xor(sum, off, 64);
    if (lane == 0) ssum[w] = sum;
    __syncthreads();
    const float inv = 1.0f / (ssum[0] + ssum[1] + ssum[2] + ssum[3]);

    ushort4 o0, o1;
    o0.x = f2bf(e[0] * inv); o0.y = f2bf(e[1] * inv);
    o0.z = f2bf(e[2] * inv); o0.w = f2bf(e[3] * inv);
    o1.x = f2bf(e[4] * inv); o1.y = f2bf(e[5] * inv);
    o1.z = f2bf(e[6] * inv); o1.w = f2bf(e[7] * inv);
    ((ushort4*)prow)[t * 2]     = o0;
    ((ushort4*)prow)[t * 2 + 1] = o1;
}

// ---------------------------------------------------------------- launch ---
extern "C" void kernel_launch(void* const* d_in, const int* in_sizes, int n_in,
                              void* d_out, int out_size, void* d_ws, size_t ws_size,
                              hipStream_t stream)
{
    const float* x = (const float*)d_in[0];
    const float* W = (const float*)d_in[1];   // [3C, C]
    float* out = (float*)d_out;

    const int B = 8, N = 2048, C = 768;
    const int M = B * N;                      // 16384
    const int kkeep = 1638;

    char* ws = (char*)d_ws;
    // layout (bytes): QKb 50.33M | Vt 25.17M | Sb 67.11M | Pb 67.11M (209.7M)
    unsigned short* QKb = (unsigned short*)(ws);                    // [M,1536]
    unsigned short* Vt  = (unsigned short*)(ws + 50331648);         // [B][C][N]
    unsigned short* Sb  = (unsigned short*)(ws + 75497472);         // [8,N,N]
    unsigned short* Pb  = (unsigned short*)(ws + 142606336);        // [8,N,N]
    // aliases inside the Sb region (dead before Sb is first written):
    unsigned short* xb = (unsigned short*)(ws + 75497472);              // [M,C]
    unsigned short* Wb = (unsigned short*)(ws + 100663296);             // [3C,C]

    // ---- merged casts: 16384*768/8 + 2304*768/8 = 1,794,048 items ----
    {
        const int nx8 = M * C / 8;              // 1,572,864
        const int nt8 = nx8 + 3 * C * C / 8;    // 1,794,048 = 7008 * 256
        cast_both<<<dim3(nt8 / 256), 256, 0, stream>>>(x, W, xb, Wb, nx8, nt8);
    }
    // ---- proj (128x96 tiles): grid (24,128) = 3072 blocks, 6 exact rounds --
    gemm_proj96<<<dim3(24, 128, 1), 256, 0, stream>>>(xb, Wb, QKb, Vt);

    // ---- QK^T (256^2 8-phase): grid (8,8,8) = 2 full 256-block rounds ----
    gemm8<6><<<dim3(8, 8, 8), 512, 0, stream>>>(
        QKb, QKb + C, 1536, 1536, (long)N * 1536, (long)N * 1536,
        Sb, 2048, (long)N * N, 1.0f / sqrtf((float)C));

    // ---- topk + softmax: all 16384 rows ----
    topk_softmax_rows<<<dim3(B * N), 256, 0, stream>>>(Sb, Pb, kkeep);

    // ---- PV: 128x96 tiles, grid (8,16,8) = 1024 blocks, 2 exact rounds ----
    gemm_pv96<<<dim3(8, 16, 8), 256, 0, stream>>>(Pb, Vt, out);
}

// Round 18
// 238.615 us; speedup vs baseline: 1.0221x; 1.0221x over previous
//
#include <hip/hip_runtime.h>
#include <hip/hip_bf16.h>
#include <math.h>

// SparseAttention: B=8, N=2048, C=768, k=1638.
// r18 = r16 verbatim (proven best, 238.6us). r17's proj96 retile regressed
// (FETCH 83->98 MB from extra panel re-reads + 24-MFMA burst inefficiency
// at K=12 tiles) and is reverted.
//   cast (merged): x->xb, W->Wb
//   proj (128^2 2-phase): QKb [M,1536] | Vt [B][C][N]
//   QK^T (256^2 8-phase, grid 512): Sb bf16 [8,N,N]
//   topk v2: histogram select + softmax -> Pb bf16     [HBM roofline]
//   PV (128x96 2-phase, grid 1024 = 2 exact rounds @ 2 blk/CU): out f32

#define BM 128
#define BN 128
#define BK 64

typedef __attribute__((ext_vector_type(8))) short bf16x8;
typedef __attribute__((ext_vector_type(4))) float f32x4;

__device__ __forceinline__ unsigned short f2bf(float f) {
    unsigned u = __float_as_uint(f);
    unsigned r = u + 0x7FFFu + ((u >> 16) & 1u);   // RN-even
    return (unsigned short)(r >> 16);
}
__device__ __forceinline__ float bf2f(unsigned short h) {
    return __uint_as_float(((unsigned)h) << 16);
}

__device__ __forceinline__ void async16(const void* g, void* l) {
    __builtin_amdgcn_global_load_lds(
        (const __attribute__((address_space(1))) void*)g,
        (__attribute__((address_space(3))) void*)l, 16, 0, 0);
}

// ======================= 128^2 2-phase core (r11, proven; proj) ============
struct GemmArgs {
    const unsigned short* A0;
    const unsigned short* B0;
    int lda, ldb;
    long batchA, batchB;
    float alpha;
};

// EPI: 5 = proj merged QKb bf16 / Vt bf16
template <int EPI, int NT>
__global__ __launch_bounds__(256) void gemm_bf16(
    GemmArgs g, void* Cp0, void* Cp1, int ldc, long batchC)
{
    __shared__ unsigned short As[2][BM * BK];
    __shared__ unsigned short Bs[2][BN * BK];

    const int nx  = gridDim.x, ny = gridDim.y;
    const int nwg = nx * ny * gridDim.z;
    const int flat = blockIdx.x + nx * (blockIdx.y + ny * blockIdx.z);
    const int lid  = (flat & 7) * (nwg >> 3) + (flat >> 3);
    const int bx   = lid % nx;
    const int byz  = lid / nx;
    const int by   = byz % ny;
    const int bz   = byz / ny;

    const int t    = threadIdx.x;
    const int wid  = t >> 6, lane = t & 63;
    const int wr   = wid >> 1, wc = wid & 1;
    const int fr   = lane & 15, fq = lane >> 4;
    const int m0   = by * BM, n0 = bx * BN;

    const unsigned short* Ab0 = g.A0 + (long)bz * g.batchA + (long)m0 * g.lda;
    const unsigned short* Bb0 = g.B0 + (long)bz * g.batchB + (long)n0 * g.ldb;

    const int srow = t >> 3;
    const int sgc  = ((t & 7) ^ (srow & 7)) * 8;
    const char* pa[4];
    const char* pb[4];
#pragma unroll
    for (int i = 0; i < 4; ++i) {
        pa[i] = (const char*)(Ab0 + (long)(i * 32 + srow) * g.lda + sgc);
        pb[i] = (const char*)(Bb0 + (long)(i * 32 + srow) * g.ldb + sgc);
    }

    int aoffs[4][2], boffs[4][2];
#pragma unroll
    for (int m = 0; m < 4; ++m) {
        const int ra = wr * 64 + m * 16 + fr;
        const int rb = wc * 64 + m * 16 + fr;
#pragma unroll
        for (int ks = 0; ks < 2; ++ks) {
            aoffs[m][ks] = ra * 128 + (((ks * 4 + fq) ^ (ra & 7)) * 16);
            boffs[m][ks] = rb * 128 + (((ks * 4 + fq) ^ (rb & 7)) * 16);
        }
    }
    const char* AsBase = (const char*)&As[0][0];
    const char* BsBase = (const char*)&Bs[0][0];

    f32x4 acc[4][4];
#pragma unroll
    for (int m = 0; m < 4; ++m)
#pragma unroll
        for (int n = 0; n < 4; ++n) acc[m][n] = (f32x4)0.f;

    const int ldsT = wid * 1024;

#define STAGE(kt, u)                                                          \
    {                                                                         \
        _Pragma("unroll")                                                     \
        for (int i = 0; i < 4; ++i) {                                         \
            async16(pa[i] + (kt) * 128,                                       \
                    (char*)&As[(u)][0] + i * 4096 + ldsT);                    \
            async16(pb[i] + (kt) * 128,                                       \
                    (char*)&Bs[(u)][0] + i * 4096 + ldsT);                    \
        }                                                                     \
    }

    STAGE(0, 0);

#pragma unroll
    for (int tt = 0; tt < NT; ++tt) {
        if (tt + 1 < NT) {
            STAGE(tt + 1, (tt + 1) & 1);
            asm volatile("s_waitcnt vmcnt(8)" ::: "memory");
        } else {
            asm volatile("s_waitcnt vmcnt(0)" ::: "memory");
        }
        __builtin_amdgcn_sched_barrier(0);
        __builtin_amdgcn_s_barrier();
        __builtin_amdgcn_sched_barrier(0);

        const int bufo = (tt & 1) * 16384;   // buffer stride = BM*BK*2B
        bf16x8 fA[4][2], fB[4][2];
#pragma unroll
        for (int m = 0; m < 4; ++m)
#pragma unroll
            for (int ks = 0; ks < 2; ++ks) {
                fA[m][ks] = *(const bf16x8*)(AsBase + bufo + aoffs[m][ks]);
                fB[m][ks] = *(const bf16x8*)(BsBase + bufo + boffs[m][ks]);
            }
        __builtin_amdgcn_s_setprio(1);
#pragma unroll
        for (int m = 0; m < 4; ++m)
#pragma unroll
            for (int n = 0; n < 4; ++n)
#pragma unroll
                for (int ks = 0; ks < 2; ++ks)
                    acc[m][n] = __builtin_amdgcn_mfma_f32_16x16x32_bf16(
                        fA[m][ks], fB[n][ks], acc[m][n], 0, 0, 0);
        __builtin_amdgcn_s_setprio(0);
        __builtin_amdgcn_sched_barrier(0);
        __builtin_amdgcn_s_barrier();
        __builtin_amdgcn_sched_barrier(0);
    }
#undef STAGE

#pragma unroll
    for (int m = 0; m < 4; ++m) {
        const int gr0 = m0 + wr * 64 + m * 16 + fq * 4;
#pragma unroll
        for (int n = 0; n < 4; ++n) {
            const int gc = n0 + wc * 64 + n * 16 + fr;
            if (EPI == 5) {   // block-uniform: BN=128 divides 1536
                if (n0 < 1536) {
                    unsigned short* H = (unsigned short*)Cp0;
#pragma unroll
                    for (int j = 0; j < 4; ++j)
                        H[(long)(gr0 + j) * ldc + gc] = f2bf(acc[m][n][j]);
                } else {
                    unsigned short* Vt = (unsigned short*)Cp1;
                    ushort4 p;
                    p.x = f2bf(acc[m][n][0]); p.y = f2bf(acc[m][n][1]);
                    p.z = f2bf(acc[m][n][2]); p.w = f2bf(acc[m][n][3]);
                    const long idx =
                        ((long)(gr0 >> 11) * 768 + (gc - 1536)) * 2048 + (gr0 & 2047);
                    *(ushort4*)&Vt[idx] = p;
                }
            }
        }
    }
}

// ================= 128x96 2-phase PV core (r16, proven) ====================
// Grid (8,16,8) = 1024 blocks @ 2 blk/CU = exactly 2 rounds (no tail idle).
// A = Pb [z][2048][2048], B = Vt [z][768][2048] (NT), out [z][2048][768] f32.
__global__ __launch_bounds__(256) void gemm_pv96(
    const unsigned short* __restrict__ Pb, const unsigned short* __restrict__ Vt,
    float* __restrict__ out)
{
    __shared__ unsigned short As[2][128 * 64];   // 2 x 16 KB
    __shared__ unsigned short Bs[2][96 * 64];    // 2 x 12 KB

    const int nx  = gridDim.x, ny = gridDim.y;   // (8,16,8)
    const int nwg = nx * ny * gridDim.z;
    const int flat = blockIdx.x + nx * (blockIdx.y + ny * blockIdx.z);
    const int lid  = (flat & 7) * (nwg >> 3) + (flat >> 3);
    const int bx   = lid % nx;
    const int byz  = lid / nx;
    const int by   = byz % ny;
    const int bz   = byz / ny;

    const int t    = threadIdx.x;
    const int wid  = t >> 6, lane = t & 63;
    const int wr   = wid >> 1, wc = wid & 1;     // 2x2 waves; wave = 64x48 out
    const int fr   = lane & 15, fq = lane >> 4;
    const int m0   = by * 128, n0 = bx * 96;

    const unsigned short* Ab0 = Pb + (long)bz * 2048 * 2048 + (long)m0 * 2048;
    const unsigned short* Bb0 = Vt + (long)bz * 768 * 2048 + (long)n0 * 2048;

    const int srow = t >> 3;                      // 0..31
    const int sgc  = ((t & 7) ^ (srow & 7)) * 8;  // inverse-swizzled source
    const char* pa[4];
    const char* pb[3];
#pragma unroll
    for (int i = 0; i < 4; ++i)
        pa[i] = (const char*)(Ab0 + (long)(i * 32 + srow) * 2048 + sgc);
#pragma unroll
    for (int i = 0; i < 3; ++i)
        pb[i] = (const char*)(Bb0 + (long)(i * 32 + srow) * 2048 + sgc);

    int aoffs[4][2], boffs[3][2];
#pragma unroll
    for (int m = 0; m < 4; ++m) {
        const int ra = wr * 64 + m * 16 + fr;     // ra&7 == fr&7
#pragma unroll
        for (int ks = 0; ks < 2; ++ks)
            aoffs[m][ks] = ra * 128 + (((ks * 4 + fq) ^ (ra & 7)) * 16);
    }
#pragma unroll
    for (int n = 0; n < 3; ++n) {
        const int rb = wc * 48 + n * 16 + fr;     // 48 % 8 == 0 -> rb&7 == fr&7
#pragma unroll
        for (int ks = 0; ks < 2; ++ks)
            boffs[n][ks] = rb * 128 + (((ks * 4 + fq) ^ (rb & 7)) * 16);
    }
    const char* AsBase = (const char*)&As[0][0];
    const char* BsBase = (const char*)&Bs[0][0];

    f32x4 acc[4][3];
#pragma unroll
    for (int m = 0; m < 4; ++m)
#pragma unroll
        for (int n = 0; n < 3; ++n) acc[m][n] = (f32x4)0.f;

    const int ldsT = wid * 1024;

    // 7 loads per tile (4 A-rounds of 32 rows + 3 B-rounds of 32 rows)
#define STAGEPV(kt, u)                                                        \
    {                                                                         \
        _Pragma("unroll")                                                     \
        for (int i = 0; i < 4; ++i)                                           \
            async16(pa[i] + (kt) * 128,                                       \
                    (char*)&As[(u)][0] + i * 4096 + ldsT);                    \
        _Pragma("unroll")                                                     \
        for (int i = 0; i < 3; ++i)                                           \
            async16(pb[i] + (kt) * 128,                                       \
                    (char*)&Bs[(u)][0] + i * 4096 + ldsT);                    \
    }

    STAGEPV(0, 0);

#pragma unroll
    for (int tt = 0; tt < 32; ++tt) {             // K = 2048 = 32 * 64
        if (tt + 1 < 32) {
            STAGEPV(tt + 1, (tt + 1) & 1);        // 7 next-tile loads in flight
            asm volatile("s_waitcnt vmcnt(7)" ::: "memory");
        } else {
            asm volatile("s_waitcnt vmcnt(0)" ::: "memory");
        }
        __builtin_amdgcn_sched_barrier(0);
        __builtin_amdgcn_s_barrier();
        __builtin_amdgcn_sched_barrier(0);

        // buffer strides DIFFER: As buf = 128*64*2 = 16384 B, Bs = 96*64*2 = 12288 B
        const int abufo = (tt & 1) * 16384;
        const int bbufo = (tt & 1) * 12288;
        bf16x8 fA[4][2], fB[3][2];
#pragma unroll
        for (int m = 0; m < 4; ++m)
#pragma unroll
            for (int ks = 0; ks < 2; ++ks)
                fA[m][ks] = *(const bf16x8*)(AsBase + abufo + aoffs[m][ks]);
#pragma unroll
        for (int n = 0; n < 3; ++n)
#pragma unroll
            for (int ks = 0; ks < 2; ++ks)
                fB[n][ks] = *(const bf16x8*)(BsBase + bbufo + boffs[n][ks]);
        __builtin_amdgcn_s_setprio(1);
#pragma unroll
        for (int m = 0; m < 4; ++m)
#pragma unroll
            for (int n = 0; n < 3; ++n)
#pragma unroll
                for (int ks = 0; ks < 2; ++ks)
                    acc[m][n] = __builtin_amdgcn_mfma_f32_16x16x32_bf16(
                        fA[m][ks], fB[n][ks], acc[m][n], 0, 0, 0);
        __builtin_amdgcn_s_setprio(0);
        __builtin_amdgcn_sched_barrier(0);
        __builtin_amdgcn_s_barrier();
        __builtin_amdgcn_sched_barrier(0);
    }
#undef STAGEPV

    // epilogue: f32, ldc = 768
    float* Cf = out + (long)bz * 2048 * 768;
#pragma unroll
    for (int m = 0; m < 4; ++m) {
        const int gr0 = m0 + wr * 64 + m * 16 + fq * 4;
#pragma unroll
        for (int n = 0; n < 3; ++n) {
            const int gc = n0 + wc * 48 + n * 16 + fr;
#pragma unroll
            for (int j = 0; j < 4; ++j)
                Cf[(long)(gr0 + j) * 768 + gc] = acc[m][n][j];
        }
    }
}

// ================== 256^2 8-phase core (r13-proven; QK^T) ==================
template <int NITER>
__global__ __launch_bounds__(512) void gemm8(
    const unsigned short* __restrict__ A0, const unsigned short* __restrict__ B0,
    int lda, int ldb, long batchA, long batchB,
    unsigned short* __restrict__ Cp0, int ldc, long batchC, float alpha)
{
    __shared__ unsigned short As[2][256 * 64];   // 2 x 32KB
    __shared__ unsigned short Bs[2][256 * 64];   // 2 x 32KB

    const int nx  = gridDim.x, ny = gridDim.y;
    const int nwg = nx * ny * gridDim.z;
    const int flat = blockIdx.x + nx * (blockIdx.y + ny * blockIdx.z);
    const int lid  = (flat & 7) * (nwg >> 3) + (flat >> 3);
    const int bx   = lid % nx;
    const int byz  = lid / nx;
    const int by   = byz % ny;
    const int bz   = byz / ny;

    const int t    = threadIdx.x;
    const int wid  = t >> 6, lane = t & 63;
    const int wr   = wid >> 2, wc = wid & 3;            // 2 x 4 waves
    const int fr   = lane & 15, fq = lane >> 4;
    const int m0   = by * 256, n0 = bx * 256;

    const unsigned short* Ab0 = A0 + (long)bz * batchA + (long)m0 * lda;
    const unsigned short* Bb0 = B0 + (long)bz * batchB + (long)n0 * ldb;

    const int srow = t >> 3;                  // 0..63
    const int sgc  = ((t & 7) ^ (srow & 7)) * 8;
    const char* pa[4];
    const char* pb[4];
#pragma unroll
    for (int i = 0; i < 4; ++i) {
        pa[i] = (const char*)(Ab0 + (long)(i * 64 + srow) * lda + sgc);
        pb[i] = (const char*)(Bb0 + (long)(i * 64 + srow) * ldb + sgc);
    }

    const int xo0 = ((fq    ) ^ (fr & 7)) * 16;
    const int xo1 = ((fq + 4) ^ (fr & 7)) * 16;
    const int abase = (wr * 128 + fr) * 128;
    const int bbase = (wc * 64  + fr) * 128;
    const char* AsB = (const char*)&As[0][0];
    const char* BsB = (const char*)&Bs[0][0];
    const int ldsT = wid * 1024;

    f32x4 acc[8][4];
#pragma unroll
    for (int m = 0; m < 8; ++m)
#pragma unroll
        for (int n = 0; n < 4; ++n) acc[m][n] = (f32x4)0.f;

#define SA_(h, kt)                                                            \
    { char* d = (char*)&As[(kt) & 1][0] + (h) * 16384 + ldsT;                 \
      async16(pa[2 * (h)]     + (long)(kt) * 128, d);                         \
      async16(pa[2 * (h) + 1] + (long)(kt) * 128, d + 8192); }
#define SB_(h, kt)                                                            \
    { char* d = (char*)&Bs[(kt) & 1][0] + (h) * 16384 + ldsT;                 \
      async16(pb[2 * (h)]     + (long)(kt) * 128, d);                         \
      async16(pb[2 * (h) + 1] + (long)(kt) * 128, d + 8192); }
#define BARRIER { __builtin_amdgcn_sched_barrier(0);                          \
                  __builtin_amdgcn_s_barrier();                               \
                  __builtin_amdgcn_sched_barrier(0); }
#define LG0 { asm volatile("s_waitcnt lgkmcnt(0)" ::: "memory");              \
              __builtin_amdgcn_sched_barrier(0); }
#define VM6 { asm volatile("s_waitcnt vmcnt(6)" ::: "memory");                \
              __builtin_amdgcn_sched_barrier(0); }
#define VM0 { asm volatile("s_waitcnt vmcnt(0)" ::: "memory");                \
              __builtin_amdgcn_sched_barrier(0); }
#define LDA4_(bp, mq)                                                         \
    _Pragma("unroll") for (int mi = 0; mi < 4; ++mi) {                        \
        fA[mi][0] = *(const bf16x8*)((bp) + abase + ((mq)*4+mi)*2048 + xo0);  \
        fA[mi][1] = *(const bf16x8*)((bp) + abase + ((mq)*4+mi)*2048 + xo1);  \
    }
#define LDB2_(bp, nb)                                                         \
    _Pragma("unroll") for (int ni = 0; ni < 2; ++ni) {                        \
        fB[(nb)+ni][0] = *(const bf16x8*)((bp) + bbase + ((nb)+ni)*2048 + xo0);\
        fB[(nb)+ni][1] = *(const bf16x8*)((bp) + bbase + ((nb)+ni)*2048 + xo1);\
    }
#define MM16_(mq, nq)                                                         \
    __builtin_amdgcn_s_setprio(1);                                            \
    _Pragma("unroll") for (int mi = 0; mi < 4; ++mi)                          \
    _Pragma("unroll") for (int ni = 0; ni < 2; ++ni)                          \
    _Pragma("unroll") for (int ks = 0; ks < 2; ++ks)                          \
        acc[(mq)*4+mi][(nq)*2+ni] = __builtin_amdgcn_mfma_f32_16x16x32_bf16(  \
            fA[mi][ks], fB[(nq)*2+ni][ks], acc[(mq)*4+mi][(nq)*2+ni], 0,0,0); \
    __builtin_amdgcn_s_setprio(0);

    // prologue: tile0 fully + tile1 {B0,B1,A0} = 14 loads; vmcnt(6) forces
    // tile0's 8 landed, leaves tile1's 6 in flight.
    SB_(0, 0); SB_(1, 0); SA_(0, 0); SA_(1, 0);
    SB_(0, 1); SB_(1, 1); SA_(0, 1);
    VM6; BARRIER;

    bf16x8 fA[4][2], fB[4][2];
#pragma unroll
    for (int it = 0; it < NITER; ++it) {
        const int tb = 2 * it + 1;
        const bool last = (it == NITER - 1);
        const char* A0p = AsB;
        const char* B0p = BsB;
        const char* A1p = AsB + 32768;
        const char* B1p = BsB + 32768;

        // ---- phases 1-4: tile 2i (buf0) ----
        LDA4_(A0p, 0); LDB2_(B0p, 0);
        SA_(1, tb);
        BARRIER; LG0; MM16_(0, 0); BARRIER;

        LDB2_(B0p, 2);
        BARRIER; LG0; MM16_(0, 1); BARRIER;

        LDA4_(A0p, 1);
        if (!last) SB_(0, tb + 1);
        BARRIER; LG0; MM16_(1, 0); BARRIER;

        if (!last) { SB_(1, tb + 1); SA_(0, tb + 1); }
        BARRIER;
        MM16_(1, 1);
        if (last) VM0 else VM6;
        BARRIER;

        // ---- phases 5-8: tile 2i+1 (buf1) ----
        LDA4_(A1p, 0); LDB2_(B1p, 0);
        if (!last) SA_(1, tb + 1);
        BARRIER; LG0; MM16_(0, 0); BARRIER;

        LDB2_(B1p, 2);
        BARRIER; LG0; MM16_(0, 1); BARRIER;

        LDA4_(A1p, 1);
        if (!last) SB_(0, tb + 2);
        BARRIER; LG0; MM16_(1, 0); BARRIER;

        if (!last) { SB_(1, tb + 2); SA_(0, tb + 2); }
        BARRIER;
        MM16_(1, 1);
        if (last) VM0 else VM6;
        BARRIER;
    }
#undef SA_
#undef SB_
#undef BARRIER
#undef LG0
#undef VM6
#undef VM0
#undef LDA4_
#undef LDB2_
#undef MM16_

    // ---- epilogue: bf16 + alpha, z-batched ----
    unsigned short* H = Cp0 + (long)bz * batchC;
#pragma unroll
    for (int m = 0; m < 8; ++m) {
        const int gr0 = m0 + wr * 128 + m * 16 + fq * 4;
#pragma unroll
        for (int n = 0; n < 4; ++n) {
            const int gc = n0 + wc * 64 + n * 16 + fr;
#pragma unroll
            for (int j = 0; j < 4; ++j)
                H[(long)(gr0 + j) * ldc + gc] = f2bf(alpha * acc[m][n][j]);
        }
    }
}

// ------------------- merged conversion: f32 -> bf16 planes -----------------
__global__ __launch_bounds__(256) void cast_both(
    const float* __restrict__ x, const float* __restrict__ W,
    unsigned short* __restrict__ xb, unsigned short* __restrict__ Wb,
    int nx8, int ntot8)
{
    const int i = blockIdx.x * 256 + threadIdx.x;
    if (i >= ntot8) return;
    const float* src;
    unsigned short* dst;
    int j;
    if (i < nx8) { src = x; dst = xb; j = i; }
    else         { src = W; dst = Wb; j = i - nx8; }
    const float4 a = ((const float4*)src)[j * 2];
    const float4 b = ((const float4*)src)[j * 2 + 1];
    ushort4 h0, h1;
    h0.x = f2bf(a.x); h0.y = f2bf(a.y); h0.z = f2bf(a.z); h0.w = f2bf(a.w);
    h1.x = f2bf(b.x); h1.y = f2bf(b.y); h1.z = f2bf(b.z); h1.w = f2bf(b.w);
    ((ushort4*)dst)[j * 2]     = h0;
    ((ushort4*)dst)[j * 2 + 1] = h1;
}

// ------------------------- top-k + softmax (v2) ----------------------------
#define ROWN 2048

__global__ __launch_bounds__(256) void topk_softmax_rows(
    const unsigned short* __restrict__ Sb, unsigned short* __restrict__ P,
    int kkeep)
{
    __shared__ __align__(16) unsigned hist[2048];
    __shared__ float    redmax[4], redmin[4], ssum[4];
    __shared__ unsigned wsum[4];
    __shared__ unsigned selBin;

    const unsigned short* row = Sb + (long)blockIdx.x * ROWN;
    unsigned short* prow = P + (long)blockIdx.x * ROWN;
    const int t    = threadIdx.x;
    const int lane = t & 63, w = t >> 6;

    float x[8];
    {
        const ushort4 a = ((const ushort4*)row)[t * 2];
        const ushort4 b = ((const ushort4*)row)[t * 2 + 1];
        x[0] = bf2f(a.x); x[1] = bf2f(a.y); x[2] = bf2f(a.z); x[3] = bf2f(a.w);
        x[4] = bf2f(b.x); x[5] = bf2f(b.y); x[6] = bf2f(b.z); x[7] = bf2f(b.w);
    }
    ((uint4*)hist)[t * 2]     = make_uint4(0, 0, 0, 0);
    ((uint4*)hist)[t * 2 + 1] = make_uint4(0, 0, 0, 0);

    float mx = x[0], mn = x[0];
#pragma unroll
    for (int j = 1; j < 8; ++j) { mx = fmaxf(mx, x[j]); mn = fminf(mn, x[j]); }
#pragma unroll
    for (int off = 32; off >= 1; off >>= 1) {
        mx = fmaxf(mx, __shfl_xor(mx, off, 64));
        mn = fminf(mn, __shfl_xor(mn, off, 64));
    }
    if (lane == 0) { redmax[w] = mx; redmin[w] = mn; }
    __syncthreads();
    mx = fmaxf(fmaxf(redmax[0], redmax[1]), fmaxf(redmax[2], redmax[3]));
    mn = fminf(fminf(redmin[0], redmin[1]), fminf(redmin[2], redmin[3]));

    const float scale = 2047.0f / fmaxf(mx - mn, 1e-30f);
    int q[8];
#pragma unroll
    for (int j = 0; j < 8; ++j) {
        int v = (int)((x[j] - mn) * scale);
        q[j] = v < 0 ? 0 : (v > 2047 ? 2047 : v);
        atomicAdd(&hist[q[j]], 1u);
    }
    __syncthreads();

    const uint4 h0 = ((const uint4*)hist)[t * 2];
    const uint4 h1 = ((const uint4*)hist)[t * 2 + 1];
    const unsigned hv[8] = { h0.x, h0.y, h0.z, h0.w, h1.x, h1.y, h1.z, h1.w };
    unsigned loc = 0;
#pragma unroll
    for (int j = 0; j < 8; ++j) loc += hv[j];
    unsigned s = loc;
#pragma unroll
    for (int off = 1; off <= 32; off <<= 1) {
        const unsigned o = __shfl_down(s, off, 64);
        s += (lane + off < 64) ? o : 0u;
    }
    if (lane == 0) wsum[w] = s;
    const unsigned texcl = s - loc;
    __syncthreads();
    unsigned above = texcl;
#pragma unroll
    for (int w2 = 0; w2 < 4; ++w2)
        if (w2 > w) above += wsum[w2];
    {
        unsigned cum = above;
        int hit = -1;
#pragma unroll
        for (int j = 7; j >= 0; --j) {
            const unsigned sp = cum;
            cum += hv[j];
            if (cum >= (unsigned)kkeep && sp < (unsigned)kkeep) hit = 8 * t + j;
        }
        if (hit >= 0) selBin = (unsigned)hit;
    }
    __syncthreads();
    const int bstar = (int)selBin;

    float e[8];
    float sum = 0.f;
#pragma unroll
    for (int j = 0; j < 8; ++j) {
        e[j] = (q[j] >= bstar) ? __expf(x[j] - mx) : 0.f;
        sum += e[j];
    }
#pragma unroll
    for (int off = 32; off >= 1; off >>= 1)
        sum += __shfl_xor(sum, off, 64);
    if (lane == 0) ssum[w] = sum;
    __syncthreads();
    const float inv = 1.0f / (ssum[0] + ssum[1] + ssum[2] + ssum[3]);

    ushort4 o0, o1;
    o0.x = f2bf(e[0] * inv); o0.y = f2bf(e[1] * inv);
    o0.z = f2bf(e[2] * inv); o0.w = f2bf(e[3] * inv);
    o1.x = f2bf(e[4] * inv); o1.y = f2bf(e[5] * inv);
    o1.z = f2bf(e[6] * inv); o1.w = f2bf(e[7] * inv);
    ((ushort4*)prow)[t * 2]     = o0;
    ((ushort4*)prow)[t * 2 + 1] = o1;
}

// ---------------------------------------------------------------- launch ---
extern "C" void kernel_launch(void* const* d_in, const int* in_sizes, int n_in,
                              void* d_out, int out_size, void* d_ws, size_t ws_size,
                              hipStream_t stream)
{
    const float* x = (const float*)d_in[0];
    const float* W = (const float*)d_in[1];   // [3C, C]
    float* out = (float*)d_out;

    const int B = 8, N = 2048, C = 768;
    const int M = B * N;                      // 16384
    const int kkeep = 1638;

    char* ws = (char*)d_ws;
    // layout (bytes): QKb 50.33M | Vt 25.17M | Sb 67.11M | Pb 67.11M (209.7M)
    unsigned short* QKb = (unsigned short*)(ws);                    // [M,1536]
    unsigned short* Vt  = (unsigned short*)(ws + 50331648);         // [B][C][N]
    unsigned short* Sb  = (unsigned short*)(ws + 75497472);         // [8,N,N]
    unsigned short* Pb  = (unsigned short*)(ws + 142606336);        // [8,N,N]
    // aliases inside the Sb region (dead before Sb is first written):
    unsigned short* xb = (unsigned short*)(ws + 75497472);              // [M,C]
    unsigned short* Wb = (unsigned short*)(ws + 100663296);             // [3C,C]

    // ---- merged casts: 16384*768/8 + 2304*768/8 = 1,794,048 items ----
    {
        const int nx8 = M * C / 8;              // 1,572,864
        const int nt8 = nx8 + 3 * C * C / 8;    // 1,794,048 = 7008 * 256
        cast_both<<<dim3(nt8 / 256), 256, 0, stream>>>(x, W, xb, Wb, nx8, nt8);
    }
    // ---- proj (128^2 core): [M,768] x [2304,768]^T, grid (18,128) ----
    {
        GemmArgs pa{};
        pa.A0 = xb; pa.B0 = Wb;
        pa.lda = C; pa.ldb = C; pa.batchA = 0; pa.batchB = 0;
        pa.alpha = 1.f;
        gemm_bf16<5, 12><<<dim3(2304 / BN, M / BM, 1), 256, 0, stream>>>(
            pa, QKb, Vt, 1536, 0);
    }
    // ---- QK^T (256^2 8-phase): grid (8,8,8) = 2 full 256-block rounds ----
    gemm8<6><<<dim3(8, 8, 8), 512, 0, stream>>>(
        QKb, QKb + C, 1536, 1536, (long)N * 1536, (long)N * 1536,
        Sb, 2048, (long)N * N, 1.0f / sqrtf((float)C));

    // ---- topk + softmax: all 16384 rows ----
    topk_softmax_rows<<<dim3(B * N), 256, 0, stream>>>(Sb, Pb, kkeep);

    // ---- PV: 128x96 tiles, grid (8,16,8) = 1024 blocks, 2 exact rounds ----
    gemm_pv96<<<dim3(8, 16, 8), 256, 0, stream>>>(Pb, Vt, out);
}